// Round 2
// baseline (489.005 us; speedup 1.0000x reference)
//
#include <hip/hip_runtime.h>

// Guided-filter detail branch, fully fused single kernel.
// out = x_norm - (box(a)*g + box(b)); all 17x17 boxes are zero-padded
// window sums / 289, computed as separable sliding-window sums in LDS.
//
// Per block: 32x32 output tile, 1024 threads (16 waves -> ~50% occupancy
// at 132 KB LDS, 1 block/CU).
//   F-region (fields, 64x64) = tile + 2*2R halo
//   A-region (a/b,   48x48)  = tile + 2R halo

constexpr int R  = 8;
constexpr int K  = 17;            // 2R+1
constexpr int TO = 32;            // output tile side
constexpr int RF = 64;            // field region side = TO + 4R
constexpr int FS = 65;            // field plane row stride (padded)
constexpr int HS = 49;            // hbox plane stride (48 cols + 1)
constexpr int AS = 49;            // a/b plane stride  (48 cols + 1)
constexpr int H2S = 33;           // hbox2 plane stride (32 cols + 1)

__global__ __launch_bounds__(1024, 4)
void guided_detail_kernel(const float* __restrict__ x, float* __restrict__ out,
                          int B, int H, int W) {
  __shared__ float lds[33104];                // 132,416 B
  float* const g0  = lds;
  float* const g1  = lds + 4160;
  float* const g2  = lds + 8320;
  float* const gry = lds + 12480;
  float* const hb0 = lds + 16640;
  float* const hb1 = lds + 19776;
  float* const hb2 = lds + 22912;
  float* const mi  = lds + 26048;
  float* const ap  = lds + 28400;
  float* const bp  = lds + 30752;

  constexpr float AREA_INV = 1.0f / 289.0f;
  constexpr float EPS = 0.001f;

  const int tid = threadIdx.x;
  const int tilesX = W / TO;
  const int tilesY = H / TO;
  const int tilesPer = tilesX * tilesY;
  const int b   = blockIdx.x / tilesPer;
  const int t   = blockIdx.x % tilesPer;
  const int ty0 = (t / tilesX) * TO;
  const int tx0 = (t % tilesX) * TO;
  const int fy0 = ty0 - 2 * R;
  const int fx0 = tx0 - 2 * R;

  const size_t plane = (size_t)H * W;
  const float* xb = x + (size_t)b * 3 * plane;

  // ---------- phase 0: load F-region, normalize+clip, gray ----------
  #pragma unroll
  for (int it = 0; it < 4; ++it) {
    const int idx = tid + it * 1024;
    const int ry = idx >> 6;
    const int rx = idx & 63;
    const int gy = fy0 + ry;
    const int gx = fx0 + rx;
    float v0 = 0.f, v1 = 0.f, v2 = 0.f;
    if (gy >= 0 && gy < H && gx >= 0 && gx < W) {
      const size_t o = (size_t)gy * W + gx;
      v0 = fminf(fmaxf(xb[o]           * 0.229f + 0.485f, 0.f), 1.f);
      v1 = fminf(fmaxf(xb[o +   plane] * 0.224f + 0.456f, 0.f), 1.f);
      v2 = fminf(fmaxf(xb[o + 2*plane] * 0.225f + 0.406f, 0.f), 1.f);
    }
    const int l = ry * FS + rx;
    g0[l] = v0; g1[l] = v1; g2[l] = v2;
    gry[l] = (v0 + v1 + v2) * (1.f / 3.f);
  }
  __syncthreads();

  // ---------- mean_i = box(gray) ----------
  { // horizontal: 64 rows x 16 col-groups of 3 outputs = 1024 items
    const int r  = tid >> 4;
    const int xs = 3 * (tid & 15);
    float s = 0.f;
    #pragma unroll
    for (int k = 0; k < K; ++k) s += gry[r * FS + xs + k];
    #pragma unroll
    for (int j = 0; j < 3; ++j) {
      hb0[r * HS + xs + j] = s;
      if (j < 2) s += gry[r * FS + xs + K + j] - gry[r * FS + xs + j];
    }
  }
  __syncthreads();
  if (tid < 768) { // vertical: 48 cols x 16 row-groups of 3
    const int col = tid % 48;
    const int r0  = (tid / 48) * 3;
    float s = 0.f;
    #pragma unroll
    for (int k = 0; k < K; ++k) s += hb0[(r0 + k) * HS + col];
    #pragma unroll
    for (int j = 0; j < 3; ++j) {
      mi[(r0 + j) * AS + col] = s * AREA_INV;
      if (j < 2) s += hb0[(r0 + K + j) * HS + col] - hb0[(r0 + j) * HS + col];
    }
  }
  __syncthreads();

  // ---------- per channel ----------
  for (int c = 0; c < 3; ++c) {
    const float* const gc = (c == 0) ? g0 : (c == 1) ? g1 : g2;

    // hbox of {g, g*gray, g*g}: 64 rows x 16 groups x 3 outputs
    {
      const int r  = tid >> 4;
      const int xs = 3 * (tid & 15);
      float sg = 0.f, si = 0.f, sq = 0.f;
      #pragma unroll
      for (int k = 0; k < K; ++k) {
        const float gv = gc[r * FS + xs + k];
        const float iv = gry[r * FS + xs + k];
        sg += gv; si += gv * iv; sq += gv * gv;
      }
      #pragma unroll
      for (int j = 0; j < 3; ++j) {
        hb0[r * HS + xs + j] = sg;
        hb1[r * HS + xs + j] = si;
        hb2[r * HS + xs + j] = sq;
        if (j < 2) {
          const float gn = gc[r * FS + xs + K + j], vn = gry[r * FS + xs + K + j];
          const float go = gc[r * FS + xs + j],     vo = gry[r * FS + xs + j];
          sg += gn - go;
          si += gn * vn - go * vo;
          sq += gn * gn - go * go;
        }
      }
    }
    __syncthreads();

    // vbox + a,b: 48 cols x 16 row-groups of 3 (A-region 48x48)
    if (tid < 768) {
      const int col = tid % 48;
      const int r0  = (tid / 48) * 3;
      float sg = 0.f, si = 0.f, sq = 0.f;
      #pragma unroll
      for (int k = 0; k < K; ++k) {
        sg += hb0[(r0 + k) * HS + col];
        si += hb1[(r0 + k) * HS + col];
        sq += hb2[(r0 + k) * HS + col];
      }
      #pragma unroll
      for (int j = 0; j < 3; ++j) {
        const int ar = r0 + j;
        const int gy = ty0 - R + ar;          // image coords of this a/b element
        const int gx = tx0 - R + col;
        float av = 0.f, bv = 0.f;
        if (gy >= 0 && gy < H && gx >= 0 && gx < W) {  // a,b zeroed outside image
          const float mg  = sg * AREA_INV;
          const float mgi = si * AREA_INV;
          const float mgg = sq * AREA_INV;
          const float miv = mi[ar * AS + col];
          av = (mgi - mg * miv) / (mgg - mg * mg + EPS);
          bv = miv - av * mg;
        }
        ap[ar * AS + col] = av;
        bp[ar * AS + col] = bv;
        if (j < 2) {
          sg += hb0[(r0 + K + j) * HS + col] - hb0[(r0 + j) * HS + col];
          si += hb1[(r0 + K + j) * HS + col] - hb1[(r0 + j) * HS + col];
          sq += hb2[(r0 + K + j) * HS + col] - hb2[(r0 + j) * HS + col];
        }
      }
    }
    __syncthreads();

    // hbox2 of a,b (reuse hb0/hb1 at stride H2S): 48 rows x 16 groups x 2
    if (tid < 768) {
      const int r  = tid / 16;        // 0..47
      const int xs = 2 * (tid & 15);  // 0..30
      float sa = 0.f, sb = 0.f;
      #pragma unroll
      for (int k = 0; k < K; ++k) {
        sa += ap[r * AS + xs + k];
        sb += bp[r * AS + xs + k];
      }
      #pragma unroll
      for (int j = 0; j < 2; ++j) {
        hb0[r * H2S + xs + j] = sa;
        hb1[r * H2S + xs + j] = sb;
        if (j < 1) {
          sa += ap[r * AS + xs + K + j] - ap[r * AS + xs + j];
          sb += bp[r * AS + xs + K + j] - bp[r * AS + xs + j];
        }
      }
    }
    __syncthreads();

    // vbox2 + final combine + store: 32x32 outputs, 1 per thread
    {
      const int col = tid & 31;
      const int row = tid >> 5;
      float sa = 0.f, sb = 0.f;
      #pragma unroll
      for (int k = 0; k < K; ++k) {
        sa += hb0[(row + k) * H2S + col];
        sb += hb1[(row + k) * H2S + col];
      }
      const float gv = gc[(row + 2 * R) * FS + (col + 2 * R)];
      const float res = gv - (sa * AREA_INV * gv + sb * AREA_INV);
      out[((size_t)b * 3 + c) * plane + (size_t)(ty0 + row) * W + (tx0 + col)] = res;
    }
    __syncthreads();
  }
}

extern "C" void kernel_launch(void* const* d_in, const int* in_sizes, int n_in,
                              void* d_out, int out_size, void* d_ws, size_t ws_size,
                              hipStream_t stream) {
  const float* x = (const float*)d_in[0];
  float* out = (float*)d_out;
  const int H = 512, W = 512;
  const int B = in_sizes[0] / (3 * H * W);
  const int grid = B * (H / TO) * (W / TO);
  guided_detail_kernel<<<grid, 1024, 0, stream>>>(x, out, B, H, W);
}

// Round 3
// 488.445 us; speedup vs baseline: 1.0011x; 1.0011x over previous
//
#include <hip/hip_runtime.h>

// Guided-filter detail branch, fully fused single kernel.
// out = x_norm - (box(a)*g + box(b)); all 17x17 boxes are zero-padded
// window sums / 289, computed as separable sliding-window sums in LDS.
//
// Per block: 32x32 output tile, 1024 threads.
// __launch_bounds__(1024) with NO min-waves arg: a 1024-thread block is
// already 4 waves/SIMD, so the VGPR cap is 128. Round-2's (1024,4) forced
// a 64-VGPR cap -> scratch spill -> 606 MB of spill writes. Do not re-add.
//   F-region (fields, 64x64) = tile + 2*2R halo
//   A-region (a/b,   48x48)  = tile + 2R halo

constexpr int R  = 8;
constexpr int K  = 17;            // 2R+1
constexpr int TO = 32;            // output tile side
constexpr int RF = 64;            // field region side = TO + 4R
constexpr int FS = 65;            // field plane row stride (padded)
constexpr int HS = 49;            // hbox plane stride (48 cols + 1)
constexpr int AS = 49;            // a/b plane stride  (48 cols + 1)
constexpr int H2S = 33;           // hbox2 plane stride (32 cols + 1)

__global__ __launch_bounds__(1024)
void guided_detail_kernel(const float* __restrict__ x, float* __restrict__ out,
                          int B, int H, int W) {
  __shared__ float lds[33104];                // 132,416 B
  float* const g0  = lds;
  float* const g1  = lds + 4160;
  float* const g2  = lds + 8320;
  float* const gry = lds + 12480;
  float* const hb0 = lds + 16640;
  float* const hb1 = lds + 19776;
  float* const hb2 = lds + 22912;
  float* const mi  = lds + 26048;
  float* const ap  = lds + 28400;
  float* const bp  = lds + 30752;

  constexpr float AREA_INV = 1.0f / 289.0f;
  constexpr float EPS = 0.001f;

  const int tid = threadIdx.x;
  const int tilesX = W / TO;
  const int tilesY = H / TO;
  const int tilesPer = tilesX * tilesY;
  const int b   = blockIdx.x / tilesPer;
  const int t   = blockIdx.x % tilesPer;
  const int ty0 = (t / tilesX) * TO;
  const int tx0 = (t % tilesX) * TO;
  const int fy0 = ty0 - 2 * R;
  const int fx0 = tx0 - 2 * R;

  const size_t plane = (size_t)H * W;
  const float* xb = x + (size_t)b * 3 * plane;

  // ---------- phase 0: load F-region, normalize+clip, gray ----------
  #pragma unroll
  for (int it = 0; it < 4; ++it) {
    const int idx = tid + it * 1024;
    const int ry = idx >> 6;
    const int rx = idx & 63;
    const int gy = fy0 + ry;
    const int gx = fx0 + rx;
    float v0 = 0.f, v1 = 0.f, v2 = 0.f;
    if (gy >= 0 && gy < H && gx >= 0 && gx < W) {
      const size_t o = (size_t)gy * W + gx;
      v0 = fminf(fmaxf(xb[o]           * 0.229f + 0.485f, 0.f), 1.f);
      v1 = fminf(fmaxf(xb[o +   plane] * 0.224f + 0.456f, 0.f), 1.f);
      v2 = fminf(fmaxf(xb[o + 2*plane] * 0.225f + 0.406f, 0.f), 1.f);
    }
    const int l = ry * FS + rx;
    g0[l] = v0; g1[l] = v1; g2[l] = v2;
    gry[l] = (v0 + v1 + v2) * (1.f / 3.f);
  }
  __syncthreads();

  // ---------- mean_i = box(gray) ----------
  { // horizontal: 64 rows x 16 col-groups of 3 outputs = 1024 items
    const int r  = tid >> 4;
    const int xs = 3 * (tid & 15);
    float s = 0.f;
    #pragma unroll
    for (int k = 0; k < K; ++k) s += gry[r * FS + xs + k];
    #pragma unroll
    for (int j = 0; j < 3; ++j) {
      hb0[r * HS + xs + j] = s;
      if (j < 2) s += gry[r * FS + xs + K + j] - gry[r * FS + xs + j];
    }
  }
  __syncthreads();
  if (tid < 768) { // vertical: 48 cols x 16 row-groups of 3
    const int col = tid % 48;
    const int r0  = (tid / 48) * 3;
    float s = 0.f;
    #pragma unroll
    for (int k = 0; k < K; ++k) s += hb0[(r0 + k) * HS + col];
    #pragma unroll
    for (int j = 0; j < 3; ++j) {
      mi[(r0 + j) * AS + col] = s * AREA_INV;
      if (j < 2) s += hb0[(r0 + K + j) * HS + col] - hb0[(r0 + j) * HS + col];
    }
  }
  __syncthreads();

  // ---------- per channel ----------
  for (int c = 0; c < 3; ++c) {
    const float* const gc = (c == 0) ? g0 : (c == 1) ? g1 : g2;

    // hbox of {g, g*gray, g*g}: 64 rows x 16 groups x 3 outputs
    {
      const int r  = tid >> 4;
      const int xs = 3 * (tid & 15);
      float sg = 0.f, si = 0.f, sq = 0.f;
      #pragma unroll
      for (int k = 0; k < K; ++k) {
        const float gv = gc[r * FS + xs + k];
        const float iv = gry[r * FS + xs + k];
        sg += gv; si += gv * iv; sq += gv * gv;
      }
      #pragma unroll
      for (int j = 0; j < 3; ++j) {
        hb0[r * HS + xs + j] = sg;
        hb1[r * HS + xs + j] = si;
        hb2[r * HS + xs + j] = sq;
        if (j < 2) {
          const float gn = gc[r * FS + xs + K + j], vn = gry[r * FS + xs + K + j];
          const float go = gc[r * FS + xs + j],     vo = gry[r * FS + xs + j];
          sg += gn - go;
          si += gn * vn - go * vo;
          sq += gn * gn - go * go;
        }
      }
    }
    __syncthreads();

    // vbox + a,b: 48 cols x 16 row-groups of 3 (A-region 48x48)
    if (tid < 768) {
      const int col = tid % 48;
      const int r0  = (tid / 48) * 3;
      float sg = 0.f, si = 0.f, sq = 0.f;
      #pragma unroll
      for (int k = 0; k < K; ++k) {
        sg += hb0[(r0 + k) * HS + col];
        si += hb1[(r0 + k) * HS + col];
        sq += hb2[(r0 + k) * HS + col];
      }
      #pragma unroll
      for (int j = 0; j < 3; ++j) {
        const int ar = r0 + j;
        const int gy = ty0 - R + ar;          // image coords of this a/b element
        const int gx = tx0 - R + col;
        float av = 0.f, bv = 0.f;
        if (gy >= 0 && gy < H && gx >= 0 && gx < W) {  // a,b zeroed outside image
          const float mg  = sg * AREA_INV;
          const float mgi = si * AREA_INV;
          const float mgg = sq * AREA_INV;
          const float miv = mi[ar * AS + col];
          av = (mgi - mg * miv) / (mgg - mg * mg + EPS);
          bv = miv - av * mg;
        }
        ap[ar * AS + col] = av;
        bp[ar * AS + col] = bv;
        if (j < 2) {
          sg += hb0[(r0 + K + j) * HS + col] - hb0[(r0 + j) * HS + col];
          si += hb1[(r0 + K + j) * HS + col] - hb1[(r0 + j) * HS + col];
          sq += hb2[(r0 + K + j) * HS + col] - hb2[(r0 + j) * HS + col];
        }
      }
    }
    __syncthreads();

    // hbox2 of a,b (reuse hb0/hb1 at stride H2S): 48 rows x 16 groups x 2
    if (tid < 768) {
      const int r  = tid / 16;        // 0..47
      const int xs = 2 * (tid & 15);  // 0..30
      float sa = 0.f, sb = 0.f;
      #pragma unroll
      for (int k = 0; k < K; ++k) {
        sa += ap[r * AS + xs + k];
        sb += bp[r * AS + xs + k];
      }
      #pragma unroll
      for (int j = 0; j < 2; ++j) {
        hb0[r * H2S + xs + j] = sa;
        hb1[r * H2S + xs + j] = sb;
        if (j < 1) {
          sa += ap[r * AS + xs + K + j] - ap[r * AS + xs + j];
          sb += bp[r * AS + xs + K + j] - bp[r * AS + xs + j];
        }
      }
    }
    __syncthreads();

    // vbox2 + final combine + store: 32x32 outputs, 1 per thread
    {
      const int col = tid & 31;
      const int row = tid >> 5;
      float sa = 0.f, sb = 0.f;
      #pragma unroll
      for (int k = 0; k < K; ++k) {
        sa += hb0[(row + k) * H2S + col];
        sb += hb1[(row + k) * H2S + col];
      }
      const float gv = gc[(row + 2 * R) * FS + (col + 2 * R)];
      const float res = gv - (sa * AREA_INV * gv + sb * AREA_INV);
      out[((size_t)b * 3 + c) * plane + (size_t)(ty0 + row) * W + (tx0 + col)] = res;
    }
    __syncthreads();
  }
}

extern "C" void kernel_launch(void* const* d_in, const int* in_sizes, int n_in,
                              void* d_out, int out_size, void* d_ws, size_t ws_size,
                              hipStream_t stream) {
  const float* x = (const float*)d_in[0];
  float* out = (float*)d_out;
  const int H = 512, W = 512;
  const int B = in_sizes[0] / (3 * H * W);
  const int grid = B * (H / TO) * (W / TO);
  guided_detail_kernel<<<grid, 1024, 0, stream>>>(x, out, B, H, W);
}

// Round 5
// 366.227 us; speedup vs baseline: 1.3353x; 1.3337x over previous
//
#include <hip/hip_runtime.h>

// Guided-filter detail branch, fully fused single kernel.
// out = x_norm - (box(a)*g + box(b)); all 17x17 boxes are zero-padded
// window sums / 289, computed as separable sliding-window sums in LDS.
//
// Per block: 32x32 output tile, 512 threads, 80.4 KB LDS -> 2 blocks/CU
// (16 waves/CU). LDS diet vs round-1: per-channel guide plane reloaded
// from global (L2-hot) instead of 3 resident planes; a/b staged through
// registers into the dead hbox planes; hbox2 overlays the dead g^2 plane.
//
// DO NOT use 1024-thread blocks here: hipcc caps them at 64 VGPR on
// gfx950 -> scratch spill -> 606 MB of spill traffic (rounds 2-3).
// DO NOT add a min-waves arg to __launch_bounds__ (same failure).

constexpr int R   = 8;
constexpr int K   = 17;           // 2R+1
constexpr int TO  = 32;           // output tile side
constexpr int RF  = 64;           // field region side = TO + 4R
constexpr int FS  = 65;           // field plane row stride (padded, odd)
constexpr int HS  = 49;           // hbox / a/b / mi row stride (odd)
constexpr int H2S = 33;           // hbox2 row stride (odd)

// LDS float offsets
constexpr int OFF_GRY = 0;        // gray      64x65 = 4160
constexpr int OFF_MI  = 4160;     // mean_i    48x49 = 2352
constexpr int OFF_GC  = 6512;     // guide ch  64x65 = 4160
constexpr int OFF_HB0 = 10672;    // hbox g    64x49 = 3136 ; reused as a-plane 48x49
constexpr int OFF_HB1 = 13808;    // hbox g*i  64x49 = 3136 ; reused as b-plane 48x49
constexpr int OFF_HBB = 16944;    // hbox g*g  64x49 = 3136 ; reused as 2x(48x33)=3168
constexpr int LDS_FLOATS = 20112; // 80,448 B -> 2 blocks/CU

__global__ __launch_bounds__(512)
void guided_detail_kernel(const float* __restrict__ x, float* __restrict__ out,
                          int B, int H, int W) {
  __shared__ float lds[LDS_FLOATS];
  float* const gry = lds + OFF_GRY;
  float* const mi  = lds + OFF_MI;
  float* const gc  = lds + OFF_GC;
  float* const hb0 = lds + OFF_HB0;
  float* const hb1 = lds + OFF_HB1;
  float* const hbB = lds + OFF_HBB;

  constexpr float AREA_INV = 1.0f / 289.0f;
  constexpr float EPS = 0.001f;

  const int tid = threadIdx.x;
  const int tilesX = W / TO;
  const int tilesPer = tilesX * (H / TO);
  const int b   = blockIdx.x / tilesPer;
  const int t   = blockIdx.x % tilesPer;
  const int ty0 = (t / tilesX) * TO;
  const int tx0 = (t % tilesX) * TO;
  const int fy0 = ty0 - 2 * R;
  const int fx0 = tx0 - 2 * R;

  const size_t plane = (size_t)H * W;
  const float* xb = x + (size_t)b * 3 * plane;

  // ---------- phase 0: gray over the 64x64 F-region ----------
  #pragma unroll
  for (int it = 0; it < 8; ++it) {
    const int idx = tid + it * 512;
    const int ry = idx >> 6;
    const int rx = idx & 63;
    const int gy = fy0 + ry;
    const int gx = fx0 + rx;
    float g = 0.f;
    if (gy >= 0 && gy < H && gx >= 0 && gx < W) {
      const size_t o = (size_t)gy * W + gx;
      const float v0 = fminf(fmaxf(xb[o]           * 0.229f + 0.485f, 0.f), 1.f);
      const float v1 = fminf(fmaxf(xb[o +   plane] * 0.224f + 0.456f, 0.f), 1.f);
      const float v2 = fminf(fmaxf(xb[o + 2*plane] * 0.225f + 0.406f, 0.f), 1.f);
      g = (v0 + v1 + v2) * (1.f / 3.f);
    }
    gry[ry * FS + rx] = g;
  }
  __syncthreads();

  // ---------- mean_i = box(gray) ----------
  { // horizontal: 64 rows x 8 col-groups x 6 outputs
    const int r  = tid >> 3;
    const int xs = 6 * (tid & 7);
    float s = 0.f;
    #pragma unroll
    for (int k = 0; k < K; ++k) s += gry[r * FS + xs + k];
    #pragma unroll
    for (int j = 0; j < 6; ++j) {
      hb0[r * HS + xs + j] = s;
      if (j < 5) s += gry[r * FS + xs + K + j] - gry[r * FS + xs + j];
    }
  }
  __syncthreads();
  if (tid < 384) { // vertical: 48 cols x 8 row-groups x 6
    const int col = tid % 48;
    const int r0  = (tid / 48) * 6;
    float s = 0.f;
    #pragma unroll
    for (int k = 0; k < K; ++k) s += hb0[(r0 + k) * HS + col];
    #pragma unroll
    for (int j = 0; j < 6; ++j) {
      mi[(r0 + j) * HS + col] = s * AREA_INV;
      if (j < 5) s += hb0[(r0 + K + j) * HS + col] - hb0[(r0 + j) * HS + col];
    }
  }
  __syncthreads();

  // ---------- per channel ----------
  for (int c = 0; c < 3; ++c) {
    const float stdc  = (c == 0) ? 0.229f : (c == 1) ? 0.224f : 0.225f;
    const float meanc = (c == 0) ? 0.485f : (c == 1) ? 0.456f : 0.406f;
    const float* xc = xb + (size_t)c * plane;

    // 3a: reload guide channel into gc (x is L2-hot from phase 0)
    #pragma unroll
    for (int it = 0; it < 8; ++it) {
      const int idx = tid + it * 512;
      const int ry = idx >> 6;
      const int rx = idx & 63;
      const int gy = fy0 + ry;
      const int gx = fx0 + rx;
      float v = 0.f;
      if (gy >= 0 && gy < H && gx >= 0 && gx < W)
        v = fminf(fmaxf(xc[(size_t)gy * W + gx] * stdc + meanc, 0.f), 1.f);
      gc[ry * FS + rx] = v;
    }
    __syncthreads();

    // 3b: hbox of {g, g*gray, g*g}: 64 rows x 8 groups x 6 outputs
    {
      const int r  = tid >> 3;
      const int xs = 6 * (tid & 7);
      float sg = 0.f, si = 0.f, sq = 0.f;
      #pragma unroll
      for (int k = 0; k < K; ++k) {
        const float gv = gc[r * FS + xs + k];
        const float iv = gry[r * FS + xs + k];
        sg += gv; si += gv * iv; sq += gv * gv;
      }
      #pragma unroll
      for (int j = 0; j < 6; ++j) {
        hb0[r * HS + xs + j] = sg;
        hb1[r * HS + xs + j] = si;
        hbB[r * HS + xs + j] = sq;
        if (j < 5) {
          const float gn = gc[r * FS + xs + K + j], vn = gry[r * FS + xs + K + j];
          const float go = gc[r * FS + xs + j],     vo = gry[r * FS + xs + j];
          sg += gn - go;
          si += gn * vn - go * vo;
          sq += gn * gn - go * go;
        }
      }
    }
    __syncthreads();

    // 3c: vbox + a,b into registers (A-region 48x48)
    float av[6], bv[6];
    int col = 0, r0 = 0;
    if (tid < 384) {
      col = tid % 48;
      r0  = (tid / 48) * 6;
      float sg = 0.f, si = 0.f, sq = 0.f;
      #pragma unroll
      for (int k = 0; k < K; ++k) {
        sg += hb0[(r0 + k) * HS + col];
        si += hb1[(r0 + k) * HS + col];
        sq += hbB[(r0 + k) * HS + col];
      }
      #pragma unroll
      for (int j = 0; j < 6; ++j) {
        const int ar = r0 + j;
        const int gy = ty0 - R + ar;          // image coords of this a/b element
        const int gx = tx0 - R + col;
        float a = 0.f, bb = 0.f;
        if (gy >= 0 && gy < H && gx >= 0 && gx < W) {  // a,b zeroed outside image
          const float mg  = sg * AREA_INV;
          const float mgi = si * AREA_INV;
          const float mgg = sq * AREA_INV;
          const float miv = mi[ar * HS + col];
          a  = (mgi - mg * miv) / (mgg - mg * mg + EPS);
          bb = miv - a * mg;
        }
        av[j] = a; bv[j] = bb;
        if (j < 5) {
          sg += hb0[(r0 + K + j) * HS + col] - hb0[(r0 + j) * HS + col];
          si += hb1[(r0 + K + j) * HS + col] - hb1[(r0 + j) * HS + col];
          sq += hbB[(r0 + K + j) * HS + col] - hbB[(r0 + j) * HS + col];
        }
      }
    }
    __syncthreads();
    // 3d: a,b -> hb0/hb1 (hbox sums now dead)
    if (tid < 384) {
      #pragma unroll
      for (int j = 0; j < 6; ++j) {
        hb0[(r0 + j) * HS + col] = av[j];
        hb1[(r0 + j) * HS + col] = bv[j];
      }
    }
    __syncthreads();

    // 3e: hbox2 of a,b -> hbB as 2 planes of 48x33 (g^2 sums dead)
    if (tid < 384) {
      const int r  = tid >> 3;        // 0..47
      const int xs = 4 * (tid & 7);   // 0..28
      float sa = 0.f, sb = 0.f;
      #pragma unroll
      for (int k = 0; k < K; ++k) {
        sa += hb0[r * HS + xs + k];
        sb += hb1[r * HS + xs + k];
      }
      #pragma unroll
      for (int j = 0; j < 4; ++j) {
        hbB[r * H2S + xs + j]        = sa;
        hbB[1584 + r * H2S + xs + j] = sb;
        if (j < 3) {
          sa += hb0[r * HS + xs + K + j] - hb0[r * HS + xs + j];
          sb += hb1[r * HS + xs + K + j] - hb1[r * HS + xs + j];
        }
      }
    }
    __syncthreads();

    // 3f: vbox2 + combine + store: 32 cols x 16 row-groups x 2
    {
      const int ocol = tid & 31;
      const int or0  = (tid >> 5) * 2;
      float sa = 0.f, sb = 0.f;
      #pragma unroll
      for (int k = 0; k < K; ++k) {
        sa += hbB[(or0 + k) * H2S + ocol];
        sb += hbB[1584 + (or0 + k) * H2S + ocol];
      }
      #pragma unroll
      for (int j = 0; j < 2; ++j) {
        const int orow = or0 + j;
        const float gv = gc[(orow + 2 * R) * FS + (ocol + 2 * R)];
        const float res = gv - (sa * AREA_INV * gv + sb * AREA_INV);
        out[((size_t)b * 3 + c) * plane + (size_t)(ty0 + orow) * W + (tx0 + ocol)] = res;
        if (j < 1) {
          sa += hbB[(or0 + K) * H2S + ocol] - hbB[or0 * H2S + ocol];
          sb += hbB[1584 + (or0 + K) * H2S + ocol] - hbB[1584 + or0 * H2S + ocol];
        }
      }
    }
    __syncthreads();  // protect gc/hb planes before next channel
  }
}

extern "C" void kernel_launch(void* const* d_in, const int* in_sizes, int n_in,
                              void* d_out, int out_size, void* d_ws, size_t ws_size,
                              hipStream_t stream) {
  const float* x = (const float*)d_in[0];
  float* out = (float*)d_out;
  const int H = 512, W = 512;
  const int B = in_sizes[0] / (3 * H * W);
  const int grid = B * (H / TO) * (W / TO);
  guided_detail_kernel<<<grid, 512, 0, stream>>>(x, out, B, H, W);
}

// Round 6
// 312.634 us; speedup vs baseline: 1.5641x; 1.1714x over previous
//
#include <hip/hip_runtime.h>

// Guided-filter detail branch, fused single kernel — f32x4/b128 LDS rewrite.
// out = x_norm - (box(a)*g + box(b)); 17x17 zero-padded box sums / 289.
//
// Round-5 lesson: kernel is LDS-instruction-throughput-bound (~5.9K scalar
// b32 wave-ops/tile ~= measured cycles). This version vectorizes every box
// phase to f32x4 (ds_read_b128/ds_write_b128), stage-1 boxes vertical-first
// with register sliding sums (products computed on the fly), horizontal
// passes 5xb128-per-4-outputs. Strides 68/52/36 (odd multiples of 4) keep
// b128 bank patterns balanced.
//
// DO NOT use 1024-thread blocks (hipcc caps at 64 VGPR -> spill, rounds 2-3).
// DO NOT chase 2 blocks/CU via LDS diet: 80.9KB still ran 1 block/CU (round 5).

typedef float f32x4 __attribute__((ext_vector_type(4)));

constexpr int K   = 17;
constexpr int TO  = 32;
constexpr int FS  = 68;   // stride for 64-wide planes and 48x68 vbox planes
constexpr int HS  = 52;   // stride for 48-wide planes
constexpr int H2S = 36;   // stride for 32-wide planes

// LDS float offsets (all multiples of 4)
constexpr int O_GRY = 0;         // gray 64x68
constexpr int O_G0  = 4352;      // g planes, 3 x 64x68 (O_G0 + c*4352)
constexpr int O_MI  = 17408;     // mean_i 48x52
constexpr int O_VA  = 19904;     // vbox(g)    48x68
constexpr int O_VB  = 23168;     // vbox(g*i)  48x68
constexpr int O_VC  = 26432;     // vbox(g*g)  48x68
constexpr int O_AP  = 29696;     // a 48x52
constexpr int O_BP  = 32192;     // b 48x52
constexpr int O_HA  = 34688;     // hbox(a) 48x36
constexpr int O_HB  = 36416;     // hbox(b) 48x36
constexpr int NLDS  = 38144;     // 152,576 B -> 1 block/CU

__global__ __launch_bounds__(512)
void guided_detail_kernel(const float* __restrict__ x, float* __restrict__ out,
                          int B, int H, int W) {
  __shared__ __align__(16) float lds[NLDS];
  constexpr float AREA_INV = 1.0f / 289.0f;
  constexpr float EPS = 0.001f;

  const int tid = threadIdx.x;
  const int tilesX = W / TO;
  const int tilesPer = tilesX * (H / TO);
  const int b   = blockIdx.x / tilesPer;
  const int t   = blockIdx.x % tilesPer;
  const int ty0 = (t / tilesX) * TO;
  const int tx0 = (t % tilesX) * TO;
  const int fy0 = ty0 - 16;
  const int fx0 = tx0 - 16;
  const size_t plane = (size_t)H * W;
  const float* xb = x + (size_t)b * 3 * plane;

#define LD4(off, stride, r, c) (*reinterpret_cast<const f32x4*>(&lds[(off) + (r)*(stride) + (c)]))
#define ST4(off, stride, r, c, v) (*reinterpret_cast<f32x4*>(&lds[(off) + (r)*(stride) + (c)]) = (v))

  // ---------- phase 0: load F-region (64x64), normalize+clip, gray ----------
  #pragma unroll
  for (int it = 0; it < 2; ++it) {
    const int chunk = tid + it * 512;
    const int ry = chunk >> 4;
    const int c0 = (chunk & 15) << 2;
    const int gy = fy0 + ry;
    const int gx = fx0 + c0;
    f32x4 n0 = {0.f,0.f,0.f,0.f}, n1 = n0, n2 = n0;
    if (gy >= 0 && gy < H) {
      f32x4 r0 = {0.f,0.f,0.f,0.f}, r1 = r0, r2 = r0;
      const bool full = (gx >= 0) && (gx + 3 < W);
      if (full) {
        const float* p = xb + (size_t)gy * W + gx;
        r0 = *reinterpret_cast<const f32x4*>(p);
        r1 = *reinterpret_cast<const f32x4*>(p + plane);
        r2 = *reinterpret_cast<const f32x4*>(p + 2 * plane);
      } else {
        #pragma unroll
        for (int j = 0; j < 4; ++j) {
          if (gx + j >= 0 && gx + j < W) {
            const size_t o = (size_t)gy * W + gx + j;
            r0[j] = xb[o]; r1[j] = xb[o + plane]; r2[j] = xb[o + 2 * plane];
          }
        }
      }
      #pragma unroll
      for (int j = 0; j < 4; ++j) {
        n0[j] = fminf(fmaxf(r0[j] * 0.229f + 0.485f, 0.f), 1.f);
        n1[j] = fminf(fmaxf(r1[j] * 0.224f + 0.456f, 0.f), 1.f);
        n2[j] = fminf(fmaxf(r2[j] * 0.225f + 0.406f, 0.f), 1.f);
      }
      if (!full) {  // zero the out-of-image lanes (must stay 0 for zero-padding)
        #pragma unroll
        for (int j = 0; j < 4; ++j)
          if (gx + j < 0 || gx + j >= W) { n0[j] = 0.f; n1[j] = 0.f; n2[j] = 0.f; }
      }
    }
    ST4(O_G0,          FS, ry, c0, n0);
    ST4(O_G0 + 4352,   FS, ry, c0, n1);
    ST4(O_G0 + 8704,   FS, ry, c0, n2);
    ST4(O_GRY,         FS, ry, c0, (n0 + n1 + n2) * (1.f / 3.f));
  }
  __syncthreads();

  // ---------- vbox(gray) -> vA: 16 colgroups x 8 rowgroups (run 6) ----------
  if (tid < 128) {
    const int cg = tid & 15, rg = tid >> 4;
    const int c0 = cg << 2, r0 = rg * 6;
    f32x4 s = {0.f,0.f,0.f,0.f};
    #pragma unroll
    for (int k = 0; k < K; ++k) s += LD4(O_GRY, FS, r0 + k, c0);
    #pragma unroll
    for (int j = 0; j < 6; ++j) {
      ST4(O_VA, FS, r0 + j, c0, s);
      if (j < 5) s += LD4(O_GRY, FS, r0 + j + K, c0) - LD4(O_GRY, FS, r0 + j, c0);
    }
  }
  __syncthreads();

  // ---------- hbox(vA) -> mi: 48 rows x 12 colgroups = 576 units ----------
  for (int u = tid; u < 576; u += 512) {
    const int ar = u / 12;
    const int c0 = (u % 12) << 2;
    f32x4 q[5];
    #pragma unroll
    for (int tt = 0; tt < 5; ++tt) q[tt] = LD4(O_VA, FS, ar, c0 + 4 * tt);
    float w[20];
    #pragma unroll
    for (int tt = 0; tt < 5; ++tt) {
      w[4*tt] = q[tt][0]; w[4*tt+1] = q[tt][1]; w[4*tt+2] = q[tt][2]; w[4*tt+3] = q[tt][3];
    }
    float s = 0.f;
    #pragma unroll
    for (int k = 0; k < K; ++k) s += w[k];
    f32x4 r;
    r[0] = s;
    r[1] = r[0] - w[0] + w[17];
    r[2] = r[1] - w[1] + w[18];
    r[3] = r[2] - w[2] + w[19];
    ST4(O_MI, HS, ar, c0, r * AREA_INV);
  }
  __syncthreads();

  // ---------- per channel ----------
  for (int c = 0; c < 3; ++c) {
    const int O_GC = O_G0 + c * 4352;

    // vtriple: vbox of {g, g*gray, g*g} on the fly; 16cg x 8rg (run 6)
    if (tid < 128) {
      const int cg = tid & 15, rg = tid >> 4;
      const int c0 = cg << 2, r0 = rg * 6;
      f32x4 sg = {0.f,0.f,0.f,0.f}, si = sg, sq = sg;
      #pragma unroll
      for (int k = 0; k < K; ++k) {
        const f32x4 gv = LD4(O_GC,  FS, r0 + k, c0);
        const f32x4 iv = LD4(O_GRY, FS, r0 + k, c0);
        sg += gv; si += gv * iv; sq += gv * gv;
      }
      #pragma unroll
      for (int j = 0; j < 6; ++j) {
        ST4(O_VA, FS, r0 + j, c0, sg);
        ST4(O_VB, FS, r0 + j, c0, si);
        ST4(O_VC, FS, r0 + j, c0, sq);
        if (j < 5) {
          const f32x4 gn = LD4(O_GC,  FS, r0 + j + K, c0);
          const f32x4 in = LD4(O_GRY, FS, r0 + j + K, c0);
          const f32x4 go = LD4(O_GC,  FS, r0 + j, c0);
          const f32x4 io = LD4(O_GRY, FS, r0 + j, c0);
          sg += gn - go;
          si += gn * in - go * io;
          sq += gn * gn - go * go;
        }
      }
    }
    __syncthreads();

    // hbox of vA/vB/vC + a,b: 48 rows x 12 colgroups = 576 units
    for (int u = tid; u < 576; u += 512) {
      const int ar = u / 12;
      const int c0 = (u % 12) << 2;
      f32x4 q[5];
      float w[20];
      f32x4 SG, SI, SQ;
      #pragma unroll
      for (int pp = 0; pp < 3; ++pp) {
        const int off = (pp == 0) ? O_VA : (pp == 1) ? O_VB : O_VC;
        #pragma unroll
        for (int tt = 0; tt < 5; ++tt) q[tt] = LD4(off, FS, ar, c0 + 4 * tt);
        #pragma unroll
        for (int tt = 0; tt < 5; ++tt) {
          w[4*tt] = q[tt][0]; w[4*tt+1] = q[tt][1]; w[4*tt+2] = q[tt][2]; w[4*tt+3] = q[tt][3];
        }
        float s = 0.f;
        #pragma unroll
        for (int k = 0; k < K; ++k) s += w[k];
        f32x4 r;
        r[0] = s;
        r[1] = r[0] - w[0] + w[17];
        r[2] = r[1] - w[1] + w[18];
        r[3] = r[2] - w[2] + w[19];
        if (pp == 0) SG = r; else if (pp == 1) SI = r; else SQ = r;
      }
      const f32x4 miv = LD4(O_MI, HS, ar, c0);
      const f32x4 mg  = SG * AREA_INV;
      const f32x4 mgi = SI * AREA_INV;
      const f32x4 mgg = SQ * AREA_INV;
      f32x4 a  = (mgi - mg * miv) / (mgg - mg * mg + EPS);
      f32x4 bb = miv - a * mg;
      // zero a,b outside the image (their boxes would otherwise be wrong)
      const int gy = ty0 - 8 + ar;
      const int gx = tx0 - 8 + c0;
      if (gy < 0 || gy >= H) {
        a = (f32x4){0.f,0.f,0.f,0.f}; bb = a;
      } else if (!(gx >= 0 && gx + 3 < W)) {
        #pragma unroll
        for (int j = 0; j < 4; ++j)
          if (gx + j < 0 || gx + j >= W) { a[j] = 0.f; bb[j] = 0.f; }
      }
      ST4(O_AP, HS, ar, c0, a);
      ST4(O_BP, HS, ar, c0, bb);
    }
    __syncthreads();

    // hbox of a,b: 48 rows x 8 colgroups = 384 units
    if (tid < 384) {
      const int ar = tid >> 3;
      const int h0 = (tid & 7) << 2;
      f32x4 q[5];
      float w[20];
      f32x4 SA, SB;
      #pragma unroll
      for (int pp = 0; pp < 2; ++pp) {
        const int off = (pp == 0) ? O_AP : O_BP;
        #pragma unroll
        for (int tt = 0; tt < 5; ++tt) q[tt] = LD4(off, HS, ar, h0 + 4 * tt);
        #pragma unroll
        for (int tt = 0; tt < 5; ++tt) {
          w[4*tt] = q[tt][0]; w[4*tt+1] = q[tt][1]; w[4*tt+2] = q[tt][2]; w[4*tt+3] = q[tt][3];
        }
        float s = 0.f;
        #pragma unroll
        for (int k = 0; k < K; ++k) s += w[k];
        f32x4 r;
        r[0] = s;
        r[1] = r[0] - w[0] + w[17];
        r[2] = r[1] - w[1] + w[18];
        r[3] = r[2] - w[2] + w[19];
        if (pp == 0) SA = r; else SB = r;
      }
      ST4(O_HA, H2S, ar, h0, SA);
      ST4(O_HB, H2S, ar, h0, SB);
    }
    __syncthreads();

    // vbox of ha,hb + combine + store: 8 colgroups x 8 rowgroups (run 4)
    if (tid < 64) {
      const int h0 = (tid & 7) << 2;
      const int or0 = (tid >> 3) << 2;
      f32x4 sa = {0.f,0.f,0.f,0.f}, sb = sa;
      #pragma unroll
      for (int k = 0; k < K; ++k) {
        sa += LD4(O_HA, H2S, or0 + k, h0);
        sb += LD4(O_HB, H2S, or0 + k, h0);
      }
      #pragma unroll
      for (int j = 0; j < 4; ++j) {
        const int orow = or0 + j;
        const f32x4 gv = LD4(O_GC, FS, orow + 16, h0 + 16);
        const f32x4 res = gv - (sa * AREA_INV * gv + sb * AREA_INV);
        float* op = out + ((size_t)b * 3 + c) * plane + (size_t)(ty0 + orow) * W + tx0 + h0;
        *reinterpret_cast<f32x4*>(op) = res;
        if (j < 3) {
          sa += LD4(O_HA, H2S, orow + K, h0) - LD4(O_HA, H2S, orow, h0);
          sb += LD4(O_HB, H2S, orow + K, h0) - LD4(O_HB, H2S, orow, h0);
        }
      }
    }
    __syncthreads();  // before next channel overwrites vA/vB/vC
  }
#undef LD4
#undef ST4
}

extern "C" void kernel_launch(void* const* d_in, const int* in_sizes, int n_in,
                              void* d_out, int out_size, void* d_ws, size_t ws_size,
                              hipStream_t stream) {
  const float* x = (const float*)d_in[0];
  float* out = (float*)d_out;
  const int H = 512, W = 512;
  const int B = in_sizes[0] / (3 * H * W);
  const int grid = B * (H / TO) * (W / TO);
  guided_detail_kernel<<<grid, 512, 0, stream>>>(x, out, B, H, W);
}

// Round 7
// 276.421 us; speedup vs baseline: 1.7691x; 1.1310x over previous
//
#include <hip/hip_runtime.h>

// Guided-filter detail branch, fused single kernel — f32x4 LDS + software-
// pipelined channel phases.
// out = x_norm - (box(a)*g + box(b)); 17x17 zero-padded box sums / 289.
//
// Round-6 lesson: ~1/3 of cycles are barrier/narrow-phase serialization
// (17 barriers, phases at 1-2 active waves). This version pipelines
// adjacent channels so every barrier phase has ~full-block work:
//   PY(c): hbox2(c) [384 thr] || vtriple(c+1) [128 thr]
//   PZ(c): vbox2(c)+store [64 thr] || hbox_ab(c+1) [448 thr]
// Plane lifetimes: vA/vB/vC dead after hbox_ab(c) -> vtriple(c+1) may
// overwrite in PY(c); ap/bp dead after hbox2(c) -> hbox_ab(c+1) in PZ(c);
// ha/hb dead after vbox2(c). Gray's vbox is staged in the ap/bp space
// (O_VG alias) during the prologue, before ap/bp first live.
//
// DO NOT use 1024-thread blocks (hipcc caps at 64 VGPR -> spill, rounds 2-3).
// DO NOT chase 2 blocks/CU via LDS diet: 80.9KB still ran 1 block/CU (round 5).

typedef float f32x4 __attribute__((ext_vector_type(4)));

constexpr int K   = 17;
constexpr int TO  = 32;
constexpr int FS  = 68;   // stride for 64-wide planes (and 48x68 vbox planes)
constexpr int HS  = 52;   // stride for 48-wide planes
constexpr int H2S = 36;   // stride for 32-wide planes

// LDS float offsets (all multiples of 4)
constexpr int O_GRY = 0;         // gray 64x68
constexpr int O_G0  = 4352;      // g planes, 3 x 64x68 (O_G0 + c*4352)
constexpr int O_MI  = 17408;     // mean_i 48x52
constexpr int O_VA  = 19904;     // vbox(g)    48x68
constexpr int O_VB  = 23168;     // vbox(g*i)  48x68
constexpr int O_VC  = 26432;     // vbox(g*g)  48x68
constexpr int O_AP  = 29696;     // a 48x52
constexpr int O_BP  = 32192;     // b 48x52
constexpr int O_HA  = 34688;     // hbox(a) 48x36
constexpr int O_HB  = 36416;     // hbox(b) 48x36
constexpr int NLDS  = 38144;     // 152,576 B -> 1 block/CU
constexpr int O_VG  = O_AP;      // prologue alias: vbox(gray) 48x68=3264 <= 4992

constexpr float AREA_INV = 1.0f / 289.0f;
constexpr float EPS = 0.001f;

#define LD4(off, stride, r, c) (*reinterpret_cast<const f32x4*>(&lds[(off) + (r)*(stride) + (c)]))
#define ST4(off, stride, r, c, v) (*reinterpret_cast<f32x4*>(&lds[(off) + (r)*(stride) + (c)]) = (v))

// 17-wide horizontal box sums for 4 consecutive outputs at (r, c0..c0+3).
__device__ __forceinline__ f32x4 hbox17(const float* lds, int off, int stride,
                                        int r, int c0) {
  f32x4 q[5];
  #pragma unroll
  for (int tt = 0; tt < 5; ++tt) q[tt] = LD4(off, stride, r, c0 + 4 * tt);
  float w[20];
  #pragma unroll
  for (int tt = 0; tt < 5; ++tt) {
    w[4*tt] = q[tt][0]; w[4*tt+1] = q[tt][1]; w[4*tt+2] = q[tt][2]; w[4*tt+3] = q[tt][3];
  }
  float s = 0.f;
  #pragma unroll
  for (int k = 0; k < K; ++k) s += w[k];
  f32x4 r4;
  r4[0] = s;
  r4[1] = r4[0] - w[0] + w[17];
  r4[2] = r4[1] - w[1] + w[18];
  r4[3] = r4[2] - w[2] + w[19];
  return r4;
}

// vbox of {g, g*gray, g*g} on the fly; local in [0,128): 16 colgroups x 8
// rowgroups, run 6. Writes vA/vB/vC.
__device__ __forceinline__ void vtriple(float* lds, int local, int O_GC) {
  const int c0 = (local & 15) << 2;
  const int r0 = (local >> 4) * 6;
  f32x4 sg = {0.f,0.f,0.f,0.f}, si = sg, sq = sg;
  #pragma unroll
  for (int k = 0; k < K; ++k) {
    const f32x4 gv = LD4(O_GC,  FS, r0 + k, c0);
    const f32x4 iv = LD4(O_GRY, FS, r0 + k, c0);
    sg += gv; si += gv * iv; sq += gv * gv;
  }
  #pragma unroll
  for (int j = 0; j < 6; ++j) {
    ST4(O_VA, FS, r0 + j, c0, sg);
    ST4(O_VB, FS, r0 + j, c0, si);
    ST4(O_VC, FS, r0 + j, c0, sq);
    if (j < 5) {
      const f32x4 gn = LD4(O_GC,  FS, r0 + j + K, c0);
      const f32x4 in = LD4(O_GRY, FS, r0 + j + K, c0);
      const f32x4 go = LD4(O_GC,  FS, r0 + j, c0);
      const f32x4 io = LD4(O_GRY, FS, r0 + j, c0);
      sg += gn - go;
      si += gn * in - go * io;
      sq += gn * gn - go * go;
    }
  }
}

// hbox of vA/vB/vC + a,b; one unit = 4 outputs at (ar, c0..c0+3).
__device__ __forceinline__ void ab_unit(float* lds, int u, int ty0, int tx0,
                                        int H, int W) {
  const int ar = u / 12;
  const int c0 = (u % 12) << 2;
  const f32x4 SG = hbox17(lds, O_VA, FS, ar, c0);
  const f32x4 SI = hbox17(lds, O_VB, FS, ar, c0);
  const f32x4 SQ = hbox17(lds, O_VC, FS, ar, c0);
  const f32x4 miv = LD4(O_MI, HS, ar, c0);
  const f32x4 mg  = SG * AREA_INV;
  const f32x4 mgi = SI * AREA_INV;
  const f32x4 mgg = SQ * AREA_INV;
  f32x4 a  = (mgi - mg * miv) / (mgg - mg * mg + EPS);
  f32x4 bb = miv - a * mg;
  // zero a,b outside the image (their boxes would otherwise be wrong)
  const int gy = ty0 - 8 + ar;
  const int gx = tx0 - 8 + c0;
  if (gy < 0 || gy >= H) {
    a = (f32x4){0.f,0.f,0.f,0.f}; bb = a;
  } else if (!(gx >= 0 && gx + 3 < W)) {
    #pragma unroll
    for (int j = 0; j < 4; ++j)
      if (gx + j < 0 || gx + j >= W) { a[j] = 0.f; bb[j] = 0.f; }
  }
  ST4(O_AP, HS, ar, c0, a);
  ST4(O_BP, HS, ar, c0, bb);
}

// hbox of a,b; local in [0,384): (ar = local>>3, h0 = (local&7)*4).
__device__ __forceinline__ void hbox2_unit(float* lds, int local) {
  const int ar = local >> 3;
  const int h0 = (local & 7) << 2;
  const f32x4 SA = hbox17(lds, O_AP, HS, ar, h0);
  const f32x4 SB = hbox17(lds, O_BP, HS, ar, h0);
  ST4(O_HA, H2S, ar, h0, SA);
  ST4(O_HB, H2S, ar, h0, SB);
}

// vbox of ha/hb + combine + store; local in [0,64): 8 colgroups x 8
// rowgroups, run 4.
__device__ __forceinline__ void vbox2_store(float* lds, int local, int O_GC,
                                            float* __restrict__ out,
                                            int ty0, int tx0, int W) {
  const int h0  = (local & 7) << 2;
  const int or0 = (local >> 3) << 2;
  f32x4 sa = {0.f,0.f,0.f,0.f}, sb = sa;
  #pragma unroll
  for (int k = 0; k < K; ++k) {
    sa += LD4(O_HA, H2S, or0 + k, h0);
    sb += LD4(O_HB, H2S, or0 + k, h0);
  }
  #pragma unroll
  for (int j = 0; j < 4; ++j) {
    const int orow = or0 + j;
    const f32x4 gv = LD4(O_GC, FS, orow + 16, h0 + 16);
    const f32x4 res = gv - (sa * AREA_INV * gv + sb * AREA_INV);
    float* op = out + (size_t)(ty0 + orow) * W + tx0 + h0;
    *reinterpret_cast<f32x4*>(op) = res;
    if (j < 3) {
      sa += LD4(O_HA, H2S, orow + K, h0) - LD4(O_HA, H2S, orow, h0);
      sb += LD4(O_HB, H2S, orow + K, h0) - LD4(O_HB, H2S, orow, h0);
    }
  }
}

__global__ __launch_bounds__(512)
void guided_detail_kernel(const float* __restrict__ x, float* __restrict__ out,
                          int B, int H, int W) {
  __shared__ __align__(16) float lds[NLDS];

  const int tid = threadIdx.x;
  const int tilesX = W / TO;
  const int tilesPer = tilesX * (H / TO);
  const int b   = blockIdx.x / tilesPer;
  const int t   = blockIdx.x % tilesPer;
  const int ty0 = (t / tilesX) * TO;
  const int tx0 = (t % tilesX) * TO;
  const int fy0 = ty0 - 16;
  const int fx0 = tx0 - 16;
  const size_t plane = (size_t)H * W;
  const float* xb = x + (size_t)b * 3 * plane;

  // ---------- P0: load F-region (64x64), normalize+clip, gray ----------
  #pragma unroll
  for (int it = 0; it < 2; ++it) {
    const int chunk = tid + it * 512;
    const int ry = chunk >> 4;
    const int c0 = (chunk & 15) << 2;
    const int gy = fy0 + ry;
    const int gx = fx0 + c0;
    f32x4 n0 = {0.f,0.f,0.f,0.f}, n1 = n0, n2 = n0;
    if (gy >= 0 && gy < H) {
      f32x4 r0 = {0.f,0.f,0.f,0.f}, r1 = r0, r2 = r0;
      const bool full = (gx >= 0) && (gx + 3 < W);
      if (full) {
        const float* p = xb + (size_t)gy * W + gx;
        r0 = *reinterpret_cast<const f32x4*>(p);
        r1 = *reinterpret_cast<const f32x4*>(p + plane);
        r2 = *reinterpret_cast<const f32x4*>(p + 2 * plane);
      } else {
        #pragma unroll
        for (int j = 0; j < 4; ++j) {
          if (gx + j >= 0 && gx + j < W) {
            const size_t o = (size_t)gy * W + gx + j;
            r0[j] = xb[o]; r1[j] = xb[o + plane]; r2[j] = xb[o + 2 * plane];
          }
        }
      }
      #pragma unroll
      for (int j = 0; j < 4; ++j) {
        n0[j] = fminf(fmaxf(r0[j] * 0.229f + 0.485f, 0.f), 1.f);
        n1[j] = fminf(fmaxf(r1[j] * 0.224f + 0.456f, 0.f), 1.f);
        n2[j] = fminf(fmaxf(r2[j] * 0.225f + 0.406f, 0.f), 1.f);
      }
      if (!full) {  // zero out-of-image lanes (must stay 0 for zero-padding)
        #pragma unroll
        for (int j = 0; j < 4; ++j)
          if (gx + j < 0 || gx + j >= W) { n0[j] = 0.f; n1[j] = 0.f; n2[j] = 0.f; }
      }
    }
    ST4(O_G0,        FS, ry, c0, n0);
    ST4(O_G0 + 4352, FS, ry, c0, n1);
    ST4(O_G0 + 8704, FS, ry, c0, n2);
    ST4(O_GRY,       FS, ry, c0, (n0 + n1 + n2) * (1.f / 3.f));
  }
  __syncthreads();

  // ---------- P1: vbox(gray) -> O_VG (48 rows x 64 cols) ----------
  if (tid < 128) {
    const int c0 = (tid & 15) << 2;
    const int r0 = (tid >> 4) * 6;
    f32x4 s = {0.f,0.f,0.f,0.f};
    #pragma unroll
    for (int k = 0; k < K; ++k) s += LD4(O_GRY, FS, r0 + k, c0);
    #pragma unroll
    for (int j = 0; j < 6; ++j) {
      ST4(O_VG, FS, r0 + j, c0, s);
      if (j < 5) s += LD4(O_GRY, FS, r0 + j + K, c0) - LD4(O_GRY, FS, r0 + j, c0);
    }
  }
  __syncthreads();

  // ---------- P2: hbox(O_VG) -> mi [tid<384] || vtriple(0) [tid>=384] ----------
  if (tid < 384) {
    for (int u = tid; u < 576; u += 384) {
      const int ar = u / 12;
      const int c0 = (u % 12) << 2;
      const f32x4 r4 = hbox17(lds, O_VG, FS, ar, c0);
      ST4(O_MI, HS, ar, c0, r4 * AREA_INV);
    }
  } else {
    vtriple(lds, tid - 384, O_G0);
  }
  __syncthreads();

  // ---------- P3: hbox_ab(0), full width ----------
  for (int u = tid; u < 576; u += 512) ab_unit(lds, u, ty0, tx0, H, W);
  __syncthreads();

  // ---------- pipelined channel loop ----------
  for (int c = 0; c < 3; ++c) {
    // PY(c): hbox2(c) [tid<384] || vtriple(c+1) [tid>=384]
    if (tid < 384) {
      hbox2_unit(lds, tid);
    } else if (c < 2) {
      vtriple(lds, tid - 384, O_G0 + (c + 1) * 4352);
    }
    __syncthreads();

    // PZ(c): vbox2(c)+store [tid>=448] || hbox_ab(c+1) [tid<448]
    if (tid >= 448) {
      vbox2_store(lds, tid - 448, O_G0 + c * 4352,
                  out + ((size_t)b * 3 + c) * plane, ty0, tx0, W);
    } else if (c < 2) {
      for (int u = tid; u < 576; u += 448) ab_unit(lds, u, ty0, tx0, H, W);
    }
    __syncthreads();
  }
}

#undef LD4
#undef ST4

extern "C" void kernel_launch(void* const* d_in, const int* in_sizes, int n_in,
                              void* d_out, int out_size, void* d_ws, size_t ws_size,
                              hipStream_t stream) {
  const float* x = (const float*)d_in[0];
  float* out = (float*)d_out;
  const int H = 512, W = 512;
  const int B = in_sizes[0] / (3 * H * W);
  const int grid = B * (H / TO) * (W / TO);
  guided_detail_kernel<<<grid, 512, 0, stream>>>(x, out, B, H, W);
}

// Round 8
// 269.529 us; speedup vs baseline: 1.8143x; 1.0256x over previous
//
#include <hip/hip_runtime.h>

// Guided-filter detail branch, fused single kernel — bank-conflict-free
// stride-64 LDS layout + software-pipelined channel phases.
// out = x_norm - (box(a)*g + box(b)); 17x17 zero-padded box sums / 289.
//
// Round-7 lesson: 22% of cycles were LDS bank conflicts, caused by odd
// strides (row shift of bank mapping) + 12-colgroup rows (quarter-waves
// straddle rows). Fix: all plane strides are multiples of 32 floats
// (row shift = 0 bank groups), and ab/mi phases run 16 units/row (768)
// so every 16-lane quarter-wave is one full row = uniform bank coverage.
// Units 12-15 of each row clamp reads to colgroup 11 (same-address
// broadcast = free) and write to cols 48-63, which are never read.
//
// DO NOT use 1024-thread blocks (hipcc caps at 64 VGPR -> spill, rounds 2-3).
// DO NOT chase 2 blocks/CU via LDS diet: 80.9KB still ran 1 block/CU (round 5).

typedef float f32x4 __attribute__((ext_vector_type(4)));

constexpr int K    = 17;
constexpr int TO   = 32;
constexpr int FSTR = 64;   // stride: 64-wide planes (gray, g, vABC, mi, a, b)
constexpr int HSTR = 32;   // stride: 32-wide planes (ha, hb)

// LDS float offsets (16B aligned)
constexpr int O_GRY = 0;          // gray 64x64 = 4096
constexpr int O_G0  = 4096;       // g planes, 3 x 64x64 (O_G0 + c*4096)
constexpr int O_MI  = 16384;      // mean_i 48x64 = 3072
constexpr int O_VA  = 19456;      // vbox(g)    48x64
constexpr int O_VB  = 22528;      // vbox(g*i)  48x64
constexpr int O_VC  = 25600;      // vbox(g*g)  48x64
constexpr int O_AP  = 28672;      // a 48x64
constexpr int O_BP  = 31744;      // b 48x64
constexpr int O_HA  = 34816;      // hbox(a) 48x32 = 1536
constexpr int O_HB  = 36352;      // hbox(b) 48x32
constexpr int NLDS  = 37888;      // 151,552 B -> 1 block/CU
constexpr int O_VG  = O_AP;       // prologue alias: vbox(gray) 48x64 = 3072

constexpr float AREA_INV = 1.0f / 289.0f;
constexpr float EPS = 0.001f;

#define LD4(off, stride, r, c) (*reinterpret_cast<const f32x4*>(&lds[(off) + (r)*(stride) + (c)]))
#define ST4(off, stride, r, c, v) (*reinterpret_cast<f32x4*>(&lds[(off) + (r)*(stride) + (c)]) = (v))

// 17-wide horizontal box sums for 4 consecutive outputs at (r, c0..c0+3).
__device__ __forceinline__ f32x4 hbox17(const float* lds, int off, int stride,
                                        int r, int c0) {
  f32x4 q[5];
  #pragma unroll
  for (int tt = 0; tt < 5; ++tt) q[tt] = LD4(off, stride, r, c0 + 4 * tt);
  float w[20];
  #pragma unroll
  for (int tt = 0; tt < 5; ++tt) {
    w[4*tt] = q[tt][0]; w[4*tt+1] = q[tt][1]; w[4*tt+2] = q[tt][2]; w[4*tt+3] = q[tt][3];
  }
  float s = 0.f;
  #pragma unroll
  for (int k = 0; k < K; ++k) s += w[k];
  f32x4 r4;
  r4[0] = s;
  r4[1] = r4[0] - w[0] + w[17];
  r4[2] = r4[1] - w[1] + w[18];
  r4[3] = r4[2] - w[2] + w[19];
  return r4;
}

// vbox of {g, g*gray, g*g} on the fly; local in [0,128): 16 colgroups x 8
// rowgroups, run 6. Writes vA/vB/vC.
__device__ __forceinline__ void vtriple(float* lds, int local, int O_GC) {
  const int c0 = (local & 15) << 2;
  const int r0 = (local >> 4) * 6;
  f32x4 sg = {0.f,0.f,0.f,0.f}, si = sg, sq = sg;
  #pragma unroll
  for (int k = 0; k < K; ++k) {
    const f32x4 gv = LD4(O_GC,  FSTR, r0 + k, c0);
    const f32x4 iv = LD4(O_GRY, FSTR, r0 + k, c0);
    sg += gv; si += gv * iv; sq += gv * gv;
  }
  #pragma unroll
  for (int j = 0; j < 6; ++j) {
    ST4(O_VA, FSTR, r0 + j, c0, sg);
    ST4(O_VB, FSTR, r0 + j, c0, si);
    ST4(O_VC, FSTR, r0 + j, c0, sq);
    if (j < 5) {
      const f32x4 gn = LD4(O_GC,  FSTR, r0 + j + K, c0);
      const f32x4 in = LD4(O_GRY, FSTR, r0 + j + K, c0);
      const f32x4 go = LD4(O_GC,  FSTR, r0 + j, c0);
      const f32x4 io = LD4(O_GRY, FSTR, r0 + j, c0);
      sg += gn - go;
      si += gn * in - go * io;
      sq += gn * gn - go * go;
    }
  }
}

// hbox of vA/vB/vC + a,b; u in [0,768): ar = u>>4, colgroup = u&15.
// Units 12-15 clamp reads to colgroup 11 (broadcast) and write garbage
// to cols 48-63 (never read) to keep quarter-waves row-uniform.
__device__ __forceinline__ void ab_unit(float* lds, int u, int ty0, int tx0,
                                        int H, int W) {
  const int ar  = u >> 4;
  const int c0  = (u & 15) << 2;
  const int c0r = (c0 > 44) ? 44 : c0;
  const f32x4 SG = hbox17(lds, O_VA, FSTR, ar, c0r);
  const f32x4 SI = hbox17(lds, O_VB, FSTR, ar, c0r);
  const f32x4 SQ = hbox17(lds, O_VC, FSTR, ar, c0r);
  const f32x4 miv = LD4(O_MI, FSTR, ar, c0r);
  const f32x4 mg  = SG * AREA_INV;
  const f32x4 mgi = SI * AREA_INV;
  const f32x4 mgg = SQ * AREA_INV;
  f32x4 a  = (mgi - mg * miv) / (mgg - mg * mg + EPS);
  f32x4 bb = miv - a * mg;
  // zero a,b outside the image (their boxes would otherwise be wrong)
  const int gy = ty0 - 8 + ar;
  const int gx = tx0 - 8 + c0r;
  if (gy < 0 || gy >= H) {
    a = (f32x4){0.f,0.f,0.f,0.f}; bb = a;
  } else if (!(gx >= 0 && gx + 3 < W)) {
    #pragma unroll
    for (int j = 0; j < 4; ++j)
      if (gx + j < 0 || gx + j >= W) { a[j] = 0.f; bb[j] = 0.f; }
  }
  ST4(O_AP, FSTR, ar, c0, a);
  ST4(O_BP, FSTR, ar, c0, bb);
}

// hbox of a,b; local in [0,384): ar = local>>3, h0 = (local&7)*4.
__device__ __forceinline__ void hbox2_unit(float* lds, int local) {
  const int ar = local >> 3;
  const int h0 = (local & 7) << 2;
  const f32x4 SA = hbox17(lds, O_AP, FSTR, ar, h0);
  const f32x4 SB = hbox17(lds, O_BP, FSTR, ar, h0);
  ST4(O_HA, HSTR, ar, h0, SA);
  ST4(O_HB, HSTR, ar, h0, SB);
}

// vbox of ha/hb + combine + store; local in [0,64): 8 colgroups x 8
// rowgroups, run 4.
__device__ __forceinline__ void vbox2_store(float* lds, int local, int O_GC,
                                            float* __restrict__ out,
                                            int ty0, int tx0, int W) {
  const int h0  = (local & 7) << 2;
  const int or0 = (local >> 3) << 2;
  f32x4 sa = {0.f,0.f,0.f,0.f}, sb = sa;
  #pragma unroll
  for (int k = 0; k < K; ++k) {
    sa += LD4(O_HA, HSTR, or0 + k, h0);
    sb += LD4(O_HB, HSTR, or0 + k, h0);
  }
  #pragma unroll
  for (int j = 0; j < 4; ++j) {
    const int orow = or0 + j;
    const f32x4 gv = LD4(O_GC, FSTR, orow + 16, h0 + 16);
    const f32x4 res = gv - (sa * AREA_INV * gv + sb * AREA_INV);
    float* op = out + (size_t)(ty0 + orow) * W + tx0 + h0;
    *reinterpret_cast<f32x4*>(op) = res;
    if (j < 3) {
      sa += LD4(O_HA, HSTR, orow + K, h0) - LD4(O_HA, HSTR, orow, h0);
      sb += LD4(O_HB, HSTR, orow + K, h0) - LD4(O_HB, HSTR, orow, h0);
    }
  }
}

__global__ __launch_bounds__(512)
void guided_detail_kernel(const float* __restrict__ x, float* __restrict__ out,
                          int B, int H, int W) {
  __shared__ __align__(16) float lds[NLDS];

  const int tid = threadIdx.x;
  const int tilesX = W / TO;
  const int tilesPer = tilesX * (H / TO);
  const int b   = blockIdx.x / tilesPer;
  const int t   = blockIdx.x % tilesPer;
  const int ty0 = (t / tilesX) * TO;
  const int tx0 = (t % tilesX) * TO;
  const int fy0 = ty0 - 16;
  const int fx0 = tx0 - 16;
  const size_t plane = (size_t)H * W;
  const float* xb = x + (size_t)b * 3 * plane;

  // ---------- P0: load F-region (64x64), normalize+clip, gray ----------
  #pragma unroll
  for (int it = 0; it < 2; ++it) {
    const int chunk = tid + it * 512;
    const int ry = chunk >> 4;
    const int c0 = (chunk & 15) << 2;
    const int gy = fy0 + ry;
    const int gx = fx0 + c0;
    f32x4 n0 = {0.f,0.f,0.f,0.f}, n1 = n0, n2 = n0;
    if (gy >= 0 && gy < H) {
      f32x4 r0 = {0.f,0.f,0.f,0.f}, r1 = r0, r2 = r0;
      const bool full = (gx >= 0) && (gx + 3 < W);
      if (full) {
        const float* p = xb + (size_t)gy * W + gx;
        r0 = *reinterpret_cast<const f32x4*>(p);
        r1 = *reinterpret_cast<const f32x4*>(p + plane);
        r2 = *reinterpret_cast<const f32x4*>(p + 2 * plane);
      } else {
        #pragma unroll
        for (int j = 0; j < 4; ++j) {
          if (gx + j >= 0 && gx + j < W) {
            const size_t o = (size_t)gy * W + gx + j;
            r0[j] = xb[o]; r1[j] = xb[o + plane]; r2[j] = xb[o + 2 * plane];
          }
        }
      }
      #pragma unroll
      for (int j = 0; j < 4; ++j) {
        n0[j] = fminf(fmaxf(r0[j] * 0.229f + 0.485f, 0.f), 1.f);
        n1[j] = fminf(fmaxf(r1[j] * 0.224f + 0.456f, 0.f), 1.f);
        n2[j] = fminf(fmaxf(r2[j] * 0.225f + 0.406f, 0.f), 1.f);
      }
      if (!full) {  // zero out-of-image lanes (must stay 0 for zero-padding)
        #pragma unroll
        for (int j = 0; j < 4; ++j)
          if (gx + j < 0 || gx + j >= W) { n0[j] = 0.f; n1[j] = 0.f; n2[j] = 0.f; }
      }
    }
    ST4(O_G0,        FSTR, ry, c0, n0);
    ST4(O_G0 + 4096, FSTR, ry, c0, n1);
    ST4(O_G0 + 8192, FSTR, ry, c0, n2);
    ST4(O_GRY,       FSTR, ry, c0, (n0 + n1 + n2) * (1.f / 3.f));
  }
  __syncthreads();

  // ---------- P1: vbox(gray) -> O_VG (48 rows x 64 cols) ----------
  if (tid < 128) {
    const int c0 = (tid & 15) << 2;
    const int r0 = (tid >> 4) * 6;
    f32x4 s = {0.f,0.f,0.f,0.f};
    #pragma unroll
    for (int k = 0; k < K; ++k) s += LD4(O_GRY, FSTR, r0 + k, c0);
    #pragma unroll
    for (int j = 0; j < 6; ++j) {
      ST4(O_VG, FSTR, r0 + j, c0, s);
      if (j < 5) s += LD4(O_GRY, FSTR, r0 + j + K, c0) - LD4(O_GRY, FSTR, r0 + j, c0);
    }
  }
  __syncthreads();

  // ---------- P2: hbox(O_VG) -> mi [tid<384] || vtriple(0) [tid>=384] ----------
  if (tid < 384) {
    for (int u = tid; u < 768; u += 384) {
      const int ar  = u >> 4;
      const int c0  = (u & 15) << 2;
      const int c0r = (c0 > 44) ? 44 : c0;
      const f32x4 r4 = hbox17(lds, O_VG, FSTR, ar, c0r);
      ST4(O_MI, FSTR, ar, c0, r4 * AREA_INV);
    }
  } else {
    vtriple(lds, tid - 384, O_G0);
  }
  __syncthreads();

  // ---------- P3: hbox_ab(0), full width ----------
  for (int u = tid; u < 768; u += 512) ab_unit(lds, u, ty0, tx0, H, W);
  __syncthreads();

  // ---------- pipelined channel loop ----------
  for (int c = 0; c < 3; ++c) {
    // PY(c): hbox2(c) [tid<384] || vtriple(c+1) [tid>=384]
    if (tid < 384) {
      hbox2_unit(lds, tid);
    } else if (c < 2) {
      vtriple(lds, tid - 384, O_G0 + (c + 1) * 4096);
    }
    __syncthreads();

    // PZ(c): vbox2(c)+store [tid>=448] || hbox_ab(c+1) [tid<448]
    if (tid >= 448) {
      vbox2_store(lds, tid - 448, O_G0 + c * 4096,
                  out + ((size_t)b * 3 + c) * plane, ty0, tx0, W);
    } else if (c < 2) {
      for (int u = tid; u < 768; u += 448) ab_unit(lds, u, ty0, tx0, H, W);
    }
    __syncthreads();
  }
}

#undef LD4
#undef ST4

extern "C" void kernel_launch(void* const* d_in, const int* in_sizes, int n_in,
                              void* d_out, int out_size, void* d_ws, size_t ws_size,
                              hipStream_t stream) {
  const float* x = (const float*)d_in[0];
  float* out = (float*)d_out;
  const int H = 512, W = 512;
  const int B = in_sizes[0] / (3 * H * W);
  const int grid = B * (H / TO) * (W / TO);
  guided_detail_kernel<<<grid, 512, 0, stream>>>(x, out, B, H, W);
}

// Round 11
// 262.195 us; speedup vs baseline: 1.8650x; 1.0280x over previous
//
#include <hip/hip_runtime.h>

// Guided-filter detail branch, fused single kernel — long-run horizontal
// boxes (run-12/run-8) + pipelined channel phases.
// out = x_norm - (box(a)*g + box(b)); 17x17 zero-padded box sums / 289.
//
// Round-8 lesson: runtime tracks LDS wave-op count (~1650/tile ~= 20K cyc).
// Horizontal boxes at run-4 re-read each elem ~5x ((R+16)/R). This version
// uses run-12 units (ab, mi) and run-8 (hbox2): 7 aligned b128 reads per
// plane per 12 outputs. Wave-ops ~1156/tile (-30%). Strides are odd
// multiples of 4 (68/52/36) so quarter-waves spanning 4 rows rotate bank
// groups (stride-64's row-uniformity is wrong for 4-units/row patterns).
//
// DO NOT use 1024-thread blocks (hipcc caps at 64 VGPR -> spill, rounds 2-3).
// DO NOT chase 2 blocks/CU via LDS diet: 80.9KB still ran 1 block/CU (round 5).

typedef float f32x4 __attribute__((ext_vector_type(4)));

constexpr int K    = 17;
constexpr int TO   = 32;
constexpr int FSTR = 68;   // 64-wide planes (gray, g, vABC, a, b)
constexpr int MSTR = 52;   // mi plane (48 wide)
constexpr int HSTR = 36;   // ha/hb planes (32 wide)

// LDS float offsets (all multiples of 4 -> 16B aligned)
constexpr int O_GRY = 0;          // gray 64x68 = 4352
constexpr int O_G0  = 4352;       // g planes, 3 x 64x68 (O_G0 + c*4352)
constexpr int O_MI  = 17408;      // mean_i 48x52 = 2496
constexpr int O_VA  = 19904;      // vbox(g)    48x68 = 3264
constexpr int O_VB  = 23168;      // vbox(g*i)  48x68
constexpr int O_VC  = 26432;      // vbox(g*g)  48x68
constexpr int O_AP  = 29696;      // a 48x68
constexpr int O_BP  = 32960;      // b 48x68
constexpr int O_HA  = 36224;      // hbox(a) 48x36 = 1728
constexpr int O_HB  = 37952;      // hbox(b) 48x36
constexpr int NLDS  = 39680;      // 158,720 B (<= 160 KiB), 1 block/CU
constexpr int O_VG  = O_AP;       // prologue alias: vbox(gray) 48x68 = 3264

constexpr float AREA_INV = 1.0f / 289.0f;
constexpr float EPS = 0.001f;

#define LD4(off, stride, r, c) (*reinterpret_cast<const f32x4*>(&lds[(off) + (r)*(stride) + (c)]))
#define ST4(off, stride, r, c, v) (*reinterpret_cast<f32x4*>(&lds[(off) + (r)*(stride) + (c)]) = (v))

struct V3 { f32x4 v[3]; };
struct V2 { f32x4 v[2]; };

// 17-wide horizontal box sums, 12 outputs at (r, c0..c0+11).
// Reads 7 aligned b128 (cols c0..c0+27); c0 must be a multiple of 4.
__device__ __forceinline__ V3 hbox12(const float* lds, int off, int stride,
                                     int r, int c0) {
  f32x4 q[7];
  #pragma unroll
  for (int tt = 0; tt < 7; ++tt) q[tt] = LD4(off, stride, r, c0 + 4 * tt);
  float w[28];
  #pragma unroll
  for (int tt = 0; tt < 7; ++tt) {
    w[4*tt] = q[tt][0]; w[4*tt+1] = q[tt][1]; w[4*tt+2] = q[tt][2]; w[4*tt+3] = q[tt][3];
  }
  float s = 0.f;
  #pragma unroll
  for (int k = 0; k < K; ++k) s += w[k];
  V3 o;
  o.v[0][0] = s;
  float cur = s;
  #pragma unroll
  for (int m = 1; m < 12; ++m) {
    cur += w[m + 16] - w[m - 1];
    o.v[m >> 2][m & 3] = cur;
  }
  return o;
}

// 17-wide horizontal box sums, 8 outputs at (r, h0..h0+7). 6 aligned b128.
__device__ __forceinline__ V2 hbox8(const float* lds, int off, int stride,
                                    int r, int h0) {
  f32x4 q[6];
  #pragma unroll
  for (int tt = 0; tt < 6; ++tt) q[tt] = LD4(off, stride, r, h0 + 4 * tt);
  float w[24];
  #pragma unroll
  for (int tt = 0; tt < 6; ++tt) {
    w[4*tt] = q[tt][0]; w[4*tt+1] = q[tt][1]; w[4*tt+2] = q[tt][2]; w[4*tt+3] = q[tt][3];
  }
  float s = 0.f;
  #pragma unroll
  for (int k = 0; k < K; ++k) s += w[k];
  V2 o;
  o.v[0][0] = s;
  float cur = s;
  #pragma unroll
  for (int m = 1; m < 8; ++m) {
    cur += w[m + 16] - w[m - 1];
    o.v[m >> 2][m & 3] = cur;
  }
  return o;
}

// vbox of {g, g*gray, g*g} on the fly; local in [0,128): 16 colgroups x 8
// rowgroups, run 6. Writes vA/vB/vC.
__device__ __forceinline__ void vtriple(float* lds, int local, int O_GC) {
  const int c0 = (local & 15) << 2;
  const int r0 = (local >> 4) * 6;
  f32x4 sg = {0.f,0.f,0.f,0.f}, si = sg, sq = sg;
  #pragma unroll
  for (int k = 0; k < K; ++k) {
    const f32x4 gv = LD4(O_GC,  FSTR, r0 + k, c0);
    const f32x4 iv = LD4(O_GRY, FSTR, r0 + k, c0);
    sg += gv; si += gv * iv; sq += gv * gv;
  }
  #pragma unroll
  for (int j = 0; j < 6; ++j) {
    ST4(O_VA, FSTR, r0 + j, c0, sg);
    ST4(O_VB, FSTR, r0 + j, c0, si);
    ST4(O_VC, FSTR, r0 + j, c0, sq);
    if (j < 5) {
      const f32x4 gn = LD4(O_GC,  FSTR, r0 + j + K, c0);
      const f32x4 in = LD4(O_GRY, FSTR, r0 + j + K, c0);
      const f32x4 go = LD4(O_GC,  FSTR, r0 + j, c0);
      const f32x4 io = LD4(O_GRY, FSTR, r0 + j, c0);
      sg += gn - go;
      si += gn * in - go * io;
      sq += gn * gn - go * go;
    }
  }
}

// hbox of vA/vB/vC + a,b; u in [0,192): ar = u>>2, c0 = (u&3)*12.
__device__ __forceinline__ void ab_unit(float* lds, int u, int ty0, int tx0,
                                        int H, int W) {
  const int ar = u >> 2;
  const int c0 = (u & 3) * 12;
  const V3 SG = hbox12(lds, O_VA, FSTR, ar, c0);
  const V3 SI = hbox12(lds, O_VB, FSTR, ar, c0);
  const V3 SQ = hbox12(lds, O_VC, FSTR, ar, c0);
  const int gy = ty0 - 8 + ar;
  const bool rowOK = (gy >= 0 && gy < H);
  #pragma unroll
  for (int v = 0; v < 3; ++v) {
    const int cv = c0 + 4 * v;
    const f32x4 miv = LD4(O_MI, MSTR, ar, cv);
    const f32x4 mg  = SG.v[v] * AREA_INV;
    const f32x4 mgi = SI.v[v] * AREA_INV;
    const f32x4 mgg = SQ.v[v] * AREA_INV;
    f32x4 a  = (mgi - mg * miv) / (mgg - mg * mg + EPS);
    f32x4 bb = miv - a * mg;
    // zero a,b outside the image (their boxes would otherwise be wrong)
    const int gx = tx0 - 8 + cv;
    if (!rowOK) {
      a = (f32x4){0.f,0.f,0.f,0.f}; bb = a;
    } else if (!(gx >= 0 && gx + 3 < W)) {
      #pragma unroll
      for (int j = 0; j < 4; ++j)
        if (gx + j < 0 || gx + j >= W) { a[j] = 0.f; bb[j] = 0.f; }
    }
    ST4(O_AP, FSTR, ar, cv, a);
    ST4(O_BP, FSTR, ar, cv, bb);
  }
}

// mi = hbox(vbox(gray))/289; u in [0,192): ar = u>>2, c0 = (u&3)*12.
__device__ __forceinline__ void mi_unit(float* lds, int u) {
  const int ar = u >> 2;
  const int c0 = (u & 3) * 12;
  const V3 S = hbox12(lds, O_VG, FSTR, ar, c0);
  #pragma unroll
  for (int v = 0; v < 3; ++v)
    ST4(O_MI, MSTR, ar, c0 + 4 * v, S.v[v] * AREA_INV);
}

// hbox of a,b; u in [0,192): ar = u>>2, h0 = (u&3)*8.
__device__ __forceinline__ void hbox2_unit(float* lds, int u) {
  const int ar = u >> 2;
  const int h0 = (u & 3) * 8;
  const V2 SA = hbox8(lds, O_AP, FSTR, ar, h0);
  const V2 SB = hbox8(lds, O_BP, FSTR, ar, h0);
  ST4(O_HA, HSTR, ar, h0,     SA.v[0]);
  ST4(O_HA, HSTR, ar, h0 + 4, SA.v[1]);
  ST4(O_HB, HSTR, ar, h0,     SB.v[0]);
  ST4(O_HB, HSTR, ar, h0 + 4, SB.v[1]);
}

// vbox of ha/hb + combine + store; local in [0,64): 8 colgroups x 8
// rowgroups, run 4.
__device__ __forceinline__ void vbox2_store(float* lds, int local, int O_GC,
                                            float* __restrict__ out,
                                            int ty0, int tx0, int W) {
  const int h0  = (local & 7) << 2;
  const int or0 = (local >> 3) << 2;
  f32x4 sa = {0.f,0.f,0.f,0.f}, sb = sa;
  #pragma unroll
  for (int k = 0; k < K; ++k) {
    sa += LD4(O_HA, HSTR, or0 + k, h0);
    sb += LD4(O_HB, HSTR, or0 + k, h0);
  }
  #pragma unroll
  for (int j = 0; j < 4; ++j) {
    const int orow = or0 + j;
    const f32x4 gv = LD4(O_GC, FSTR, orow + 16, h0 + 16);
    const f32x4 res = gv - (sa * AREA_INV * gv + sb * AREA_INV);
    float* op = out + (size_t)(ty0 + orow) * W + tx0 + h0;
    *reinterpret_cast<f32x4*>(op) = res;
    if (j < 3) {
      sa += LD4(O_HA, HSTR, orow + K, h0) - LD4(O_HA, HSTR, orow, h0);
      sb += LD4(O_HB, HSTR, orow + K, h0) - LD4(O_HB, HSTR, orow, h0);
    }
  }
}

__global__ __launch_bounds__(512)
void guided_detail_kernel(const float* __restrict__ x, float* __restrict__ out,
                          int B, int H, int W) {
  __shared__ __align__(16) float lds[NLDS];

  const int tid = threadIdx.x;
  const int tilesX = W / TO;
  const int tilesPer = tilesX * (H / TO);
  const int b   = blockIdx.x / tilesPer;
  const int t   = blockIdx.x % tilesPer;
  const int ty0 = (t / tilesX) * TO;
  const int tx0 = (t % tilesX) * TO;
  const int fy0 = ty0 - 16;
  const int fx0 = tx0 - 16;
  const size_t plane = (size_t)H * W;
  const float* xb = x + (size_t)b * 3 * plane;

  // ---------- P0: load F-region (64x64), normalize+clip, gray ----------
  #pragma unroll
  for (int it = 0; it < 2; ++it) {
    const int chunk = tid + it * 512;
    const int ry = chunk >> 4;
    const int c0 = (chunk & 15) << 2;
    const int gy = fy0 + ry;
    const int gx = fx0 + c0;
    f32x4 n0 = {0.f,0.f,0.f,0.f}, n1 = n0, n2 = n0;
    if (gy >= 0 && gy < H) {
      f32x4 r0 = {0.f,0.f,0.f,0.f}, r1 = r0, r2 = r0;
      const bool full = (gx >= 0) && (gx + 3 < W);
      if (full) {
        const float* p = xb + (size_t)gy * W + gx;
        r0 = *reinterpret_cast<const f32x4*>(p);
        r1 = *reinterpret_cast<const f32x4*>(p + plane);
        r2 = *reinterpret_cast<const f32x4*>(p + 2 * plane);
      } else {
        #pragma unroll
        for (int j = 0; j < 4; ++j) {
          if (gx + j >= 0 && gx + j < W) {
            const size_t o = (size_t)gy * W + gx + j;
            r0[j] = xb[o]; r1[j] = xb[o + plane]; r2[j] = xb[o + 2 * plane];
          }
        }
      }
      #pragma unroll
      for (int j = 0; j < 4; ++j) {
        n0[j] = fminf(fmaxf(r0[j] * 0.229f + 0.485f, 0.f), 1.f);
        n1[j] = fminf(fmaxf(r1[j] * 0.224f + 0.456f, 0.f), 1.f);
        n2[j] = fminf(fmaxf(r2[j] * 0.225f + 0.406f, 0.f), 1.f);
      }
      if (!full) {  // zero out-of-image lanes (must stay 0 for zero-padding)
        #pragma unroll
        for (int j = 0; j < 4; ++j)
          if (gx + j < 0 || gx + j >= W) { n0[j] = 0.f; n1[j] = 0.f; n2[j] = 0.f; }
      }
    }
    ST4(O_G0,        FSTR, ry, c0, n0);
    ST4(O_G0 + 4352, FSTR, ry, c0, n1);
    ST4(O_G0 + 8704, FSTR, ry, c0, n2);
    ST4(O_GRY,       FSTR, ry, c0, (n0 + n1 + n2) * (1.f / 3.f));
  }
  __syncthreads();

  // ---------- P1: vbox(gray) -> O_VG (48 rows x 64 cols) ----------
  if (tid < 128) {
    const int c0 = (tid & 15) << 2;
    const int r0 = (tid >> 4) * 6;
    f32x4 s = {0.f,0.f,0.f,0.f};
    #pragma unroll
    for (int k = 0; k < K; ++k) s += LD4(O_GRY, FSTR, r0 + k, c0);
    #pragma unroll
    for (int j = 0; j < 6; ++j) {
      ST4(O_VG, FSTR, r0 + j, c0, s);
      if (j < 5) s += LD4(O_GRY, FSTR, r0 + j + K, c0) - LD4(O_GRY, FSTR, r0 + j, c0);
    }
  }
  __syncthreads();

  // ---------- P2: mi [tid<192] || vtriple(0) [tid>=384] ----------
  if (tid < 192) {
    mi_unit(lds, tid);
  } else if (tid >= 384) {
    vtriple(lds, tid - 384, O_G0);
  }
  __syncthreads();

  // ---------- P3: hbox_ab(0) ----------
  if (tid < 192) ab_unit(lds, tid, ty0, tx0, H, W);
  __syncthreads();

  // ---------- pipelined channel loop ----------
  for (int c = 0; c < 3; ++c) {
    // PY(c): hbox2(c) [tid<192] || vtriple(c+1) [tid>=384]
    if (tid < 192) {
      hbox2_unit(lds, tid);
    } else if (tid >= 384 && c < 2) {
      vtriple(lds, tid - 384, O_G0 + (c + 1) * 4352);
    }
    __syncthreads();

    // PZ(c): vbox2(c)+store [tid>=448] || hbox_ab(c+1) [tid<192]
    if (tid >= 448) {
      vbox2_store(lds, tid - 448, O_G0 + c * 4352,
                  out + ((size_t)b * 3 + c) * plane, ty0, tx0, W);
    } else if (tid < 192 && c < 2) {
      ab_unit(lds, tid, ty0, tx0, H, W);
    }
    __syncthreads();
  }
}

#undef LD4
#undef ST4

extern "C" void kernel_launch(void* const* d_in, const int* in_sizes, int n_in,
                              void* d_out, int out_size, void* d_ws, size_t ws_size,
                              hipStream_t stream) {
  const float* x = (const float*)d_in[0];
  float* out = (float*)d_out;
  const int H = 512, W = 512;
  const int B = in_sizes[0] / (3 * H * W);
  const int grid = B * (H / TO) * (W / TO);
  guided_detail_kernel<<<grid, 512, 0, stream>>>(x, out, B, H, W);
}